// Round 11
// baseline (2381.542 us; speedup 1.0000x reference)
//
#include <hip/hip_runtime.h>
#include <hip/hip_bf16.h>
#include <hip/hip_fp16.h>

// ---------------------------------------------------------------------------
// MGAN forward. fp16 MFMA; persistent flag-synced LSTM scan (single launch).
//   B=256 S=128 A=8 L=32 D=H=300 NC=3 VOCAB=32000
// MFMA 16x16x32_f16 fragment scheme (validated rounds 2-10):
//   A-frag: lane holds A[m = l&15][k = (l>>4)*8 + j]
//   B-frag (B^T [n][k]): lane holds B[n = l&15][k = (l>>4)*8 + j]
//   D:      lane,reg r -> D[m = (l>>4)*4 + r][n = l&15]
// P stored scan-order (validated r8-10): Pscan[d][t'][b][1216].
// Whh fragment-major (validated r8-10); preloaded to REGISTERS (160 VGPR).
// Scan (round 11): ONE regular launch, 304 co-resident blocks (no LDS,
// 256 thr) — grid (19 js, 2 d, 8 z) where z<4: ctx group mg=z, z>=4: asp.
// Cross-block h handoff inside a (which,d,mg) group of 19 js-blocks via
// agent-scope release/acquire flags (release = wbl2 after syncthreads store
// drain; acquire = inv before h reads). c-state in registers (block-owned).
// NOTE rounds 4/5 post-mortem: hipLaunchCooperativeKernel silently fails in
// graph capture — this uses a plain launch (304 blocks trivially co-reside).
// ---------------------------------------------------------------------------

#define NB   256
#define NS   128
#define NA   8
#define NL   32
#define ND   300
#define NH   300
#define NPAD  2432      // 2*4*304 (bias/Wih padded n-space)
#define KP    320
#define TOK_CTX 32768
#define TOK_ALL 34816
#define PD    1216      // per-dir gate row: 4*304

typedef _Float16 half8 __attribute__((ext_vector_type(8)));
typedef float    f32x4 __attribute__((ext_vector_type(4)));

// ---------------- K0: sequence lengths ----------------
__global__ void k_lengths(const int* __restrict__ text, const int* __restrict__ aspect,
                          const int* __restrict__ left, int* __restrict__ lens) {
  int b = threadIdx.x;
  if (b >= NB) return;
  int ll = 0; for (int i = 0; i < NL; i++) ll += (left[b*NL + i] != 0);
  int cl = 0; for (int i = 0; i < NS; i++) cl += (text[b*NS + i] != 0);
  int al = 0; for (int i = 0; i < NA; i++) al += (aspect[b*NA + i] != 0);
  lens[b] = ll; lens[NB + b] = cl; lens[2*NB + b] = al;
}

// ---------------- converters ----------------
__global__ void k_cvt_emb(const float* __restrict__ emb, _Float16* __restrict__ emb16) {
  const long N = (long)32000 * KP;
  for (long i = (long)blockIdx.x*blockDim.x + threadIdx.x; i < N; i += (long)gridDim.x*blockDim.x) {
    long v = i / KP; int k = (int)(i - v*KP);
    emb16[i] = (k < ND) ? (_Float16)emb[v*ND + k] : (_Float16)0.f;
  }
}

// y==0: Wih16 row-major [d][g][304][320]; y==1: Whh_frag fragment-major;
// y==2: bias_sum[NPAD]
__global__ void k_cvt_w(const float* __restrict__ Wih_f, const float* __restrict__ Wih_b,
                        const float* __restrict__ Whh_f, const float* __restrict__ Whh_b,
                        const float* __restrict__ bih_f, const float* __restrict__ bhh_f,
                        const float* __restrict__ bih_b, const float* __restrict__ bhh_b,
                        _Float16* __restrict__ Wih16, _Float16* __restrict__ Whh_frag,
                        float* __restrict__ bias_sum) {
  int y = blockIdx.y;
  if (y == 0) {
    const long N = (long)NPAD * KP;
    for (long i = (long)blockIdx.x*blockDim.x + threadIdx.x; i < N; i += (long)gridDim.x*blockDim.x) {
      long row = i / KP; int k = (int)(i - row*KP);
      int d = (int)(row / PD); int rem = (int)(row - (long)d*PD);
      int g = rem / 304; int jj = rem - g*304;
      float v = 0.f;
      if (jj < NH && k < NH) {
        const float* src = d ? Wih_b : Wih_f;
        v = src[(long)(g*NH + jj)*NH + k];
      }
      Wih16[i] = (_Float16)v;
    }
  } else if (y == 1) {
    // Whh_frag[(((d*4+g)*19 + jt)*10 + k0)*512 + l*8 + e]
    //   n = jt*16 + (l&15), k = k0*32 + (l>>4)*8 + e
    const long N = (long)2*4*19*10*512;   // 778240
    for (long i = (long)blockIdx.x*blockDim.x + threadIdx.x; i < N; i += (long)gridDim.x*blockDim.x) {
      long q = i >> 9; int r512 = (int)(i & 511);
      int l = r512 >> 3, e = r512 & 7;
      int k0 = (int)(q % 10); q /= 10;
      int jt = (int)(q % 19); q /= 19;
      int g  = (int)(q % 4);  int d = (int)(q / 4);
      int n = jt*16 + (l & 15);
      int k = k0*32 + (l >> 4)*8 + e;
      float v = 0.f;
      if (n < NH && k < NH) {
        const float* src = d ? Whh_b : Whh_f;
        v = src[(long)(g*NH + n)*NH + k];
      }
      Whh_frag[i] = (_Float16)v;
    }
  } else {
    for (int i = blockIdx.x*blockDim.x + threadIdx.x; i < NPAD; i += gridDim.x*blockDim.x) {
      int d = i / PD; int rem = i - d*PD;
      int g = rem / 304; int jj = rem - g*304;
      float v = 0.f;
      if (jj < NH) {
        v = d ? (bih_b[g*NH + jj] + bhh_b[g*NH + jj]) : (bih_f[g*NH + jj] + bhh_f[g*NH + jj]);
      }
      bias_sum[i] = v;
    }
  }
}

// ---------------- K1: input projection GEMM, writes SCAN-ORDER P ----------------
// m enumerated b-major: ctx m = t*256 + b (m<32768); asp m-32768 = t*256 + b.
// grid (272 m, 19 n), 256 thr. Dest: Pc[d][t'][b][1216] / Pa[...]
__global__ __launch_bounds__(256) void k_inproj(
    const _Float16* __restrict__ emb16, const int* __restrict__ text, const int* __restrict__ aspect,
    const _Float16* __restrict__ Wih16, const float* __restrict__ bias_sum,
    const int* __restrict__ lens,
    _Float16* __restrict__ Pc, _Float16* __restrict__ Pa)
{
  const int l = threadIdx.x & 63, w = threadIdx.x >> 6;
  const int m0 = blockIdx.x * 128, n0 = blockIdx.y * 128;
  const int lrow = l & 15, lk = (l >> 4) * 8;
  __shared__ __align__(16) _Float16 Cs[128*136];

  const _Float16* ap[2];
  #pragma unroll
  for (int q = 0; q < 2; q++) {
    int r = m0 + (2*w + q)*16 + lrow;
    int tok;
    if (r < TOK_CTX) { int t = r >> 8, b = r & 255; tok = text[b*NS + t]; }
    else { int rr = r - TOK_CTX; int t = rr >> 8, b = rr & 255; tok = aspect[b*NA + t]; }
    ap[q] = emb16 + (long)tok*KP + lk;
  }
  const _Float16* bp[8];
  #pragma unroll
  for (int nt = 0; nt < 8; nt++)
    bp[nt] = Wih16 + (long)(n0 + nt*16 + lrow)*KP + lk;

  f32x4 acc[2][8];
  #pragma unroll
  for (int q = 0; q < 2; q++)
    #pragma unroll
    for (int nt = 0; nt < 8; nt++) acc[q][nt] = (f32x4){0.f,0.f,0.f,0.f};

  #pragma unroll
  for (int k0 = 0; k0 < 10; k0++) {
    half8 a0 = *(const half8*)(ap[0] + k0*32);
    half8 a1 = *(const half8*)(ap[1] + k0*32);
    #pragma unroll
    for (int nt = 0; nt < 8; nt++) {
      half8 bb = *(const half8*)(bp[nt] + k0*32);
      acc[0][nt] = __builtin_amdgcn_mfma_f32_16x16x32_f16(a0, bb, acc[0][nt], 0, 0, 0);
      acc[1][nt] = __builtin_amdgcn_mfma_f32_16x16x32_f16(a1, bb, acc[1][nt], 0, 0, 0);
    }
  }

  #pragma unroll
  for (int nt = 0; nt < 8; nt++) {
    float bias = bias_sum[n0 + nt*16 + lrow];
    #pragma unroll
    for (int q = 0; q < 2; q++) {
      int lr = (2*w + q)*16 + (l>>4)*4;
      #pragma unroll
      for (int r = 0; r < 4; r++)
        Cs[(lr + r)*136 + nt*16 + lrow] = (_Float16)(acc[q][nt][r] + bias);
    }
  }
  __syncthreads();
  // relayout store: each thread one row-half (64 cols, within one dir since 1216=19*64)
  const int row = threadIdx.x >> 1, ch = (threadIdx.x & 1)*64;
  const int r = m0 + row;
  int b, t, T, len; _Float16* Pdst;
  if (r < TOK_CTX) { t = r >> 8; b = r & 255; T = NS; Pdst = Pc; len = lens[NB + b]; }
  else { int rr = r - TOK_CTX; t = rr >> 8; b = rr & 255; T = NA; Pdst = Pa; len = lens[2*NB + b]; }
  const int c0 = n0 + ch;
  const int d = (c0 >= PD) ? 1 : 0;
  const int rem0 = c0 - d*PD;
  int tp = t; bool doit = true;
  if (d == 1) { if (t < len) tp = len - 1 - t; else doit = false; }
  if (doit) {
    size_t base = ((size_t)(d*T + tp)*256 + b)*PD + rem0;
    #pragma unroll
    for (int i = 0; i < 8; i++) {
      half8 v = *(const half8*)&Cs[row*136 + ch + i*8];
      *(half8*)&Pdst[base + i*8] = v;
    }
  }
}

// ---------------- K2: persistent LSTM scan, flag-synced (ONE launch) ----------------
// grid (19 js, 2 d, 8 z), 256 thr = 4 waves. z<4: ctx group mg=z; z>=4: asp mg=z-4.
// Sync group = the 19 js-blocks of one (which,d,mg). c-state in registers.
__global__ __launch_bounds__(256) void k_lstm_scan(
    const _Float16* __restrict__ Pc, const _Float16* __restrict__ Pa,
    const _Float16* __restrict__ Whh_frag, const int* __restrict__ lens,
    _Float16* __restrict__ hcarC, _Float16* __restrict__ hseqC,
    _Float16* __restrict__ hcarA, _Float16* __restrict__ hseqA,
    int* __restrict__ flags)   // [NS*8 ctx | NA*8 asp], zeroed before launch
{
  const int l = threadIdx.x & 63, w = threadIdx.x >> 6;
  const int js = blockIdx.x, d = blockIdx.y;
  const int which = blockIdx.z >> 2;
  const int mg = blockIdx.z & 3;
  const int T = which ? NA : NS;
  const _Float16* __restrict__ Pbase = which ? Pa : Pc;
  const int* __restrict__ lenp = lens + (which ? 2*NB : NB);
  _Float16* __restrict__ hcar = which ? hcarA : hcarC;
  _Float16* __restrict__ hseq = which ? hseqA : hseqC;
  int* __restrict__ flg = flags + (which ? NS*8 : 0);

  const int lrow = l & 15, lk = (l >> 4)*8, mrow = l >> 4;
  const int b0 = mg*64 + w*16;
  const int jj = js*16 + lrow;

  // preload this block's Whh fragments into registers (40 x half8 = 160 VGPR)
  half8 wf[10][4];
  #pragma unroll
  for (int k0 = 0; k0 < 10; k0++)
    #pragma unroll
    for (int g = 0; g < 4; g++)
      wf[k0][g] = *(const half8*)(Whh_frag +
          ((((size_t)(d*4 + g)*19 + js)*10 + k0) << 9) + l*8);

  float cst[4];
  int   lenv[4];
  #pragma unroll
  for (int r = 0; r < 4; r++) { cst[r] = 0.f; lenv[r] = lenp[b0 + mrow*4 + r]; }

  for (int t = 0; t < T; t++) {
    // ---- prefetch this step's P gates (valid since inproj ran; hides spin) ----
    const size_t slab = (size_t)(d*T + t)*256;
    float pre[4][4];
    #pragma unroll
    for (int r = 0; r < 4; r++) {
      const int b = b0 + mrow*4 + r;
      const _Float16* Pr = Pbase + (slab + b)*PD + js*16 + lrow;
      pre[r][0] = (float)Pr[0];
      pre[r][1] = (float)Pr[304];
      pre[r][2] = (float)Pr[608];
      pre[r][3] = (float)Pr[912];
    }

    f32x4 acc[4];
    #pragma unroll
    for (int g = 0; g < 4; g++) acc[g] = (f32x4){0.f,0.f,0.f,0.f};
    float hp[4] = {0.f, 0.f, 0.f, 0.f};

    if (t > 0) {
      if (threadIdx.x == 0) {
        int* fp = &flg[((t-1)*2 + d)*4 + mg];
        while (__hip_atomic_load(fp, __ATOMIC_ACQUIRE, __HIP_MEMORY_SCOPE_AGENT) < 19)
          __builtin_amdgcn_s_sleep(8);
      }
      __syncthreads();   // all threads ordered after the acquire
      const _Float16* __restrict__ hr = hcar + ((size_t)(((t-1)&1)*2 + d)*256)*KP;
      #pragma unroll
      for (int r = 0; r < 4; r++)
        hp[r] = (float)hr[(size_t)(b0 + mrow*4 + r)*KP + jj];
      const _Float16* hb = hr + (size_t)(b0 + lrow)*KP + lk;
      #pragma unroll
      for (int k0 = 0; k0 < 10; k0++) {
        half8 a = *(const half8*)(hb + k0*32);
        #pragma unroll
        for (int g = 0; g < 4; g++)
          acc[g] = __builtin_amdgcn_mfma_f32_16x16x32_f16(a, wf[k0][g], acc[g], 0, 0, 0);
      }
    }

    // ---- pointwise: 4 cells per thread ----
    _Float16* __restrict__ hw = hcar + ((size_t)((t&1)*2 + d)*256)*KP;
    #pragma unroll
    for (int r = 0; r < 4; r++) {
      const int b = b0 + mrow*4 + r;
      float gi = acc[0][r] + pre[r][0];
      float gf = acc[1][r] + pre[r][1];
      float gg = acc[2][r] + pre[r][2];
      float go = acc[3][r] + pre[r][3];
      float si = 1.f/(1.f + __expf(-gi));
      float sf = 1.f/(1.f + __expf(-gf));
      float so = 1.f/(1.f + __expf(-go));
      float cn = sf*cst[r] + si*tanhf(gg);
      float hn = so*tanhf(cn);
      bool mt = t < lenv[r];
      float h2 = mt ? hn : hp[r];
      cst[r] = mt ? cn : cst[r];
      hw[(size_t)b*KP + jj] = (_Float16)h2;
      if (jj < NH)
        hseq[(((size_t)d*T + t)*256 + b)*NH + jj] = (_Float16)(mt ? hn : 0.f);
    }

    __syncthreads();   // drains all threads' stores (vmcnt0) before release
    if (threadIdx.x == 0)
      __hip_atomic_fetch_add(&flg[(t*2 + d)*4 + mg], 1,
                             __ATOMIC_RELEASE, __HIP_MEMORY_SCOPE_AGENT);
  }
}

// ---------------- K3: combine + position weight -> ctx[b][s][600] ----------------
__global__ __launch_bounds__(320) void k_combine_ctx(
    const _Float16* __restrict__ hseq, const int* __restrict__ lens, _Float16* __restrict__ ctx)
{
  const int s = blockIdx.x, bg = blockIdx.y, tid = threadIdx.x;
  if (tid >= NH) return;
  for (int bq = 0; bq < 16; bq++) {
    int b = bg*16 + bq;
    int cl = lens[NB + b], ll = lens[b], al = lens[2*NB + b];
    float clf = (float)cl, llf = (float)ll, alf = (float)al;
    float tf = (float)s, denom = clf - alf + 1.f;
    float wgt = (tf < llf) ? (1.f - (llf - tf)/denom)
              : (tf < llf + alf) ? 0.f
              : (tf < clf) ? (1.f - (tf - llf - alf + 1.f)/denom) : 0.f;
    float vf = (float)hseq[((size_t)s*256 + b)*NH + tid];
    int tb0 = cl - 1 - s; int tb = tb0 < 0 ? 0 : (tb0 > NS-1 ? NS-1 : tb0);
    float vb = (s < cl) ? (float)hseq[((size_t)(NS + tb)*256 + b)*NH + tid] : 0.f;
    ctx[((size_t)b*NS + s)*600 + tid]      = (_Float16)(vf * wgt);
    ctx[((size_t)b*NS + s)*600 + NH + tid] = (_Float16)(vb * wgt);
  }
}

// ---------------- K3b: transpose ctx -> ctxT[b][j][s] ----------------
__global__ void k_transpose(const _Float16* __restrict__ ctx, _Float16* __restrict__ ctxT) {
  __shared__ _Float16 tl[32][34];
  int b = blockIdx.x, s0 = blockIdx.y*32, j0 = blockIdx.z*32;
  int c = threadIdx.x & 31, r0 = threadIdx.x >> 5;
  #pragma unroll
  for (int i = 0; i < 4; i++) {
    int r = r0 + i*8;
    int j = j0 + c;
    tl[r][c] = (j < 600) ? ctx[((long)b*NS + s0 + r)*600 + j] : (_Float16)0.f;
  }
  __syncthreads();
  #pragma unroll
  for (int i = 0; i < 4; i++) {
    int r = r0 + i*8;
    int j = j0 + r;
    if (j < 600) ctxT[((long)b*600 + j)*NS + s0 + c] = tl[c][r];
  }
}

// ---------------- K4: aspect combine -> aspc[b][a][600] ----------------
__global__ __launch_bounds__(320) void k_combine_asp(
    const _Float16* __restrict__ hseq, const int* __restrict__ lens, _Float16* __restrict__ aspc)
{
  int b = blockIdx.x, tid = threadIdx.x;
  if (tid >= NH) return;
  int al = lens[2*NB + b];
  for (int a = 0; a < NA; a++) {
    float vf = (float)hseq[((size_t)a*256 + b)*NH + tid];
    int tb0 = al - 1 - a; int tb = tb0 < 0 ? 0 : (tb0 > NA-1 ? NA-1 : tb0);
    float vb = (a < al) ? (float)hseq[((size_t)(NA + tb)*256 + b)*NH + tid] : 0.f;
    aspc[((size_t)b*NA + a)*600 + tid]      = (_Float16)vf;
    aspc[((size_t)b*NA + a)*600 + NH + tid] = (_Float16)vb;
  }
}

// ---------------- K5: c_avg, a_avg ----------------
__global__ void k_avg(const _Float16* __restrict__ ctx, const _Float16* __restrict__ aspc,
                      const int* __restrict__ lens, float* __restrict__ c_avg, float* __restrict__ a_avg) {
  int b = blockIdx.x, j = threadIdx.x;
  if (j >= 600) return;
  float ac = 0.f;
  for (int s = 0; s < NS; s++) ac += (float)ctx[((long)b*NS + s)*600 + j];
  c_avg[(long)b*600 + j] = ac / (float)lens[NB + b];
  float aa = 0.f;
  for (int a = 0; a < NA; a++) aa += (float)aspc[((long)b*NA + a)*600 + j];
  a_avg[(long)b*600 + j] = aa / (float)lens[2*NB + b];
}

// ---------------- K6: s1 = a_avg@w1 ; s2 = c_avg@w2 ----------------
__global__ void k_sw(const float* __restrict__ a_avg, const float* __restrict__ c_avg,
                     const float* __restrict__ w1, const float* __restrict__ w2,
                     float* __restrict__ s1, float* __restrict__ s2) {
  __shared__ float src[8][600];
  int bg = blockIdx.x * 8, which = blockIdx.y, tid = threadIdx.x;
  const float* sp = which ? c_avg : a_avg;
  const float* w  = which ? w2 : w1;
  float* outp     = which ? s2 : s1;
  for (int u = tid; u < 8*600; u += 640) {
    int q = u / 600, dd = u - q*600;
    src[q][dd] = sp[(long)(bg + q)*600 + dd];
  }
  __syncthreads();
  int j = tid;
  if (j >= 600) return;
  float acc[8] = {0,0,0,0,0,0,0,0};
  for (int dd = 0; dd < 600; dd++) {
    float wvv = w[dd*600 + j];
    #pragma unroll
    for (int q = 0; q < 8; q++) acc[q] += src[q][dd] * wvv;
  }
  #pragma unroll
  for (int q = 0; q < 8; q++) outp[(long)(bg + q)*600 + j] = acc[q];
}

// ---------------- K7: alpha1 + mca ----------------
__global__ __launch_bounds__(128) void k_att_ctx(const _Float16* __restrict__ ctxT,
    const _Float16* __restrict__ ctx, const float* __restrict__ s1, float* __restrict__ mca) {
  int b = blockIdx.x, tid = threadIdx.x;
  __shared__ float sv[600];
  __shared__ float red[128];
  __shared__ float mx, sm;
  for (int u = tid; u < 600; u += 128) sv[u] = s1[(long)b*600 + u];
  __syncthreads();
  float sc = 0.f;
  for (int dd = 0; dd < 600; dd++) sc += sv[dd] * (float)ctxT[((long)b*600 + dd)*NS + tid];
  red[tid] = sc; __syncthreads();
  if (tid == 0) { float m = -1e30f; for (int i = 0; i < 128; i++) m = fmaxf(m, red[i]); mx = m; }
  __syncthreads();
  float e = __expf(sc - mx);
  red[tid] = e; __syncthreads();
  if (tid == 0) { float s = 0.f; for (int i = 0; i < 128; i++) s += red[i]; sm = s; }
  __syncthreads();
  float alpha = e / sm;
  red[tid] = alpha; __syncthreads();
  for (int i = 0; i < 5; i++) {
    int j = tid + i*128;
    if (j < 600) {
      float acc = 0.f;
      for (int s2 = 0; s2 < NS; s2++) acc += red[s2] * (float)ctx[((long)b*NS + s2)*600 + j];
      mca[(long)b*600 + j] = acc;
    }
  }
}

// ---------------- K8: alpha2 + mcc ----------------
__global__ void k_att_asp(const _Float16* __restrict__ aspc, const float* __restrict__ s2,
                          float* __restrict__ mcc) {
  int b = blockIdx.x, tid = threadIdx.x, wvv = tid >> 6, lane = tid & 63;
  __shared__ float sv[600];
  __shared__ float sc8[8];
  for (int u = tid; u < 600; u += 512) sv[u] = s2[(long)b*600 + u];
  __syncthreads();
  float p = 0.f;
  for (int dd = lane; dd < 600; dd += 64) p += sv[dd] * (float)aspc[((long)b*NA + wvv)*600 + dd];
  #pragma unroll
  for (int off = 32; off; off >>= 1) p += __shfl_down(p, off);
  if (lane == 0) sc8[wvv] = p;
  __syncthreads();
  float m = -1e30f;
  #pragma unroll
  for (int a = 0; a < 8; a++) m = fmaxf(m, sc8[a]);
  float es[8]; float ssum = 0.f;
  #pragma unroll
  for (int a = 0; a < 8; a++) { es[a] = __expf(sc8[a] - m); ssum += es[a]; }
  float inv = 1.f / ssum;
  for (int i = 0; i < 2; i++) {
    int j = tid + i*512;
    if (j < 600) {
      float acc = 0.f;
      #pragma unroll
      for (int a = 0; a < 8; a++) acc += es[a]*inv * (float)aspc[((long)b*NA + a)*600 + j];
      mcc[(long)b*600 + j] = acc;
    }
  }
}

// ---------------- K9: u tensor -> mfa, mfc ----------------
__global__ __launch_bounds__(128) void k_u(const _Float16* __restrict__ ctxT, const _Float16* __restrict__ ctx,
    const _Float16* __restrict__ aspc, const float* __restrict__ fc1_w, const float* __restrict__ fc1_b,
    float* __restrict__ mfa, float* __restrict__ mfc) {
  int b = blockIdx.x, tid = threadIdx.x;   // tid == s
  __shared__ __align__(16) float aspl[4800];
  __shared__ float ua8[8];
  __shared__ float red[128];
  __shared__ float qa8[8];
  __shared__ float mx1, sm1;
  __shared__ float pal[128][8];
  for (int u = tid; u < 4800; u += 128) {
    int a = u / 600, dd = u - a*600;
    aspl[dd*8 + a] = (float)aspc[((long)b*NA + a)*600 + dd];
  }
  __syncthreads();
  const float* wc = fc1_w;
  const float* wa = fc1_w + 600;
  const float* wm = fc1_w + 1200;
  {
    int wvv = tid >> 6, lane = tid & 63;
    for (int q = 0; q < 4; q++) {
      int a = wvv*4 + q;
      float p = 0.f;
      for (int dd = lane; dd < 600; dd += 64) p += wa[dd] * aspl[dd*8 + a];
      #pragma unroll
      for (int off = 32; off; off >>= 1) p += __shfl_down(p, off);
      if (lane == 0) ua8[a] = p;
    }
  }
  __syncthreads();
  float x8[8] = {0,0,0,0,0,0,0,0};
  float uc = 0.f;
  for (int dd = 0; dd < 600; dd++) {
    float cv = (float)ctxT[((long)b*600 + dd)*NS + tid];
    uc += cv * wc[dd];
    float cm = cv * wm[dd];
    float4 a03 = *(const float4*)&aspl[dd*8];
    float4 a47 = *(const float4*)&aspl[dd*8 + 4];
    x8[0] += cm*a03.x; x8[1] += cm*a03.y; x8[2] += cm*a03.z; x8[3] += cm*a03.w;
    x8[4] += cm*a47.x; x8[5] += cm*a47.y; x8[6] += cm*a47.z; x8[7] += cm*a47.w;
  }
  float fb = fc1_b[0];
  float u8v[8]; float umax = -1e30f;
  #pragma unroll
  for (int a = 0; a < 8; a++) { u8v[a] = uc + ua8[a] + x8[a] + fb; umax = fmaxf(umax, u8v[a]); }
  float pa[8]; float psum = 0.f;
  #pragma unroll
  for (int a = 0; a < 8; a++) { pa[a] = __expf(u8v[a] - umax); psum += pa[a]; }
  float pin = 1.f / psum;
  #pragma unroll
  for (int a = 0; a < 8; a++) pal[tid][a] = pa[a] * pin;
  red[tid] = umax;
  __syncthreads();
  if (tid == 0) { float m = -1e30f; for (int i = 0; i < 128; i++) m = fmaxf(m, red[i]); mx1 = m; }
  if (tid < 8) { float s = 0.f; for (int i = 0; i < 128; i++) s += pal[i][tid]; qa8[tid] = s * (1.f/128.f); }
  __syncthreads();
  float e = __expf(umax - mx1);
  red[tid] = e;
  __syncthreads();
  if (tid == 0) { float s = 0.f; for (int i = 0; i < 128; i++) s += red[i]; sm1 = s; }
  __syncthreads();
  float alpha = e / sm1;
  red[tid] = alpha;
  __syncthreads();
  for (int i = 0; i < 5; i++) {
    int j = tid + i*128;
    if (j < 600) {
      float am = 0.f;
      for (int s2 = 0; s2 < NS; s2++) am += red[s2] * (float)ctx[((long)b*NS + s2)*600 + j];
      float4 a03 = *(const float4*)&aspl[j*8];
      float4 a47 = *(const float4*)&aspl[j*8 + 4];
      mfa[(long)b*600 + j] = am;
      mfc[(long)b*600 + j] = qa8[0]*a03.x + qa8[1]*a03.y + qa8[2]*a03.z + qa8[3]*a03.w
                           + qa8[4]*a47.x + qa8[5]*a47.y + qa8[6]*a47.z + qa8[7]*a47.w;
    }
  }
}

// ---------------- K10: final FC + softmax ----------------
__global__ void k_final(const float* __restrict__ mca, const float* __restrict__ mcc,
                        const float* __restrict__ mfa, const float* __restrict__ mfc,
                        const float* __restrict__ fc2_w, const float* __restrict__ fc2_b,
                        float* __restrict__ out) {
  int b = blockIdx.x, tid = threadIdx.x, c = tid >> 6, lane = tid & 63;
  __shared__ float lg[3];
  float p = 0.f;
  for (int u = lane; u < 2400; u += 64) {
    int piece = u / 600;
    int jj = u - piece*600;
    const float* src = (piece == 0) ? mca : (piece == 1) ? mcc : (piece == 2) ? mfa : mfc;
    p += src[(long)b*600 + jj] * fc2_w[c*2400 + u];
  }
  #pragma unroll
  for (int off = 32; off; off >>= 1) p += __shfl_down(p, off);
  if (lane == 0) lg[c] = p + fc2_b[c];
  __syncthreads();
  if (tid == 0) {
    float m = fmaxf(lg[0], fmaxf(lg[1], lg[2]));
    float e0 = __expf(lg[0]-m), e1 = __expf(lg[1]-m), e2 = __expf(lg[2]-m);
    float s = e0 + e1 + e2;
    out[b*3 + 0] = e0/s; out[b*3 + 1] = e1/s; out[b*3 + 2] = e2/s;
  }
}

// ---------------- host ----------------
extern "C" void kernel_launch(void* const* d_in, const int* in_sizes, int n_in,
                              void* d_out, int out_size, void* d_ws, size_t ws_size,
                              hipStream_t stream)
{
  const int*   text    = (const int*)d_in[0];
  const int*   aspect  = (const int*)d_in[1];
  const int*   left    = (const int*)d_in[2];
  const float* emb     = (const float*)d_in[3];
  const float* Wih_f   = (const float*)d_in[4];
  const float* Whh_f   = (const float*)d_in[5];
  const float* bih_f   = (const float*)d_in[6];
  const float* bhh_f   = (const float*)d_in[7];
  const float* Wih_b   = (const float*)d_in[8];
  const float* Whh_b   = (const float*)d_in[9];
  const float* bih_b   = (const float*)d_in[10];
  const float* bhh_b   = (const float*)d_in[11];
  const float* w1      = (const float*)d_in[12];
  const float* w2      = (const float*)d_in[13];
  const float* fc1_w   = (const float*)d_in[14];
  const float* fc1_b   = (const float*)d_in[15];
  const float* fc2_w   = (const float*)d_in[16];
  const float* fc2_b   = (const float*)d_in[17];
  float* out = (float*)d_out;

  char* base = (char*)d_ws;
  size_t off = 0;
  auto alloc = [&](size_t bytes) -> void* {
    void* p = base + off;
    off = (off + bytes + 255) & ~(size_t)255;
    return p;
  };
  int*      lens     = (int*)     alloc(3 * NB * sizeof(int));
  int*      flags    = (int*)     alloc((size_t)(NS + NA)*8 * sizeof(int));       // 4.25 KB
  float*    bias_sum = (float*)   alloc(NPAD * sizeof(float));
  _Float16* Wih16    = (_Float16*)alloc((size_t)NPAD*KP * sizeof(_Float16));      // 1.56 MB
  _Float16* Whh_frag = (_Float16*)alloc((size_t)2*4*19*10*512 * sizeof(_Float16));// 1.56 MB
  _Float16* hcarC    = (_Float16*)alloc((size_t)2*2*NB*KP * sizeof(_Float16));    // 655 KB
  _Float16* hcarA    = (_Float16*)alloc((size_t)2*2*NB*KP * sizeof(_Float16));
  float*    c_avg    = (float*)   alloc((size_t)NB*600 * sizeof(float));
  float*    a_avg    = (float*)   alloc((size_t)NB*600 * sizeof(float));
  float*    s1       = (float*)   alloc((size_t)NB*600 * sizeof(float));
  float*    s2       = (float*)   alloc((size_t)NB*600 * sizeof(float));
  float*    mca      = (float*)   alloc((size_t)NB*600 * sizeof(float));
  float*    mcc      = (float*)   alloc((size_t)NB*600 * sizeof(float));
  float*    mfa      = (float*)   alloc((size_t)NB*600 * sizeof(float));
  float*    mfc      = (float*)   alloc((size_t)NB*600 * sizeof(float));
  // hseqC region (39.3 MB) doubles as emb16 (20.5 MB) before the scans
  _Float16* hseqC    = (_Float16*)alloc((size_t)2*NS*NB*NH * sizeof(_Float16));
  _Float16* emb16    = hseqC;
  _Float16* hseqA    = (_Float16*)alloc((size_t)2*NA*NB*NH * sizeof(_Float16));   // 2.46 MB
  // BIG region: Pc (159.4 MB) + Pa (10 MB); ctx/ctxT/aspc (81 MB) overlay Pc later
  _Float16* Pc = (_Float16*)alloc((size_t)2*NS*NB*PD * sizeof(_Float16));
  _Float16* Pa = (_Float16*)alloc((size_t)2*NA*NB*PD * sizeof(_Float16));
  _Float16* ctx  = Pc;
  _Float16* ctxT = ctx  + (size_t)NB*NS*600;
  _Float16* aspc = ctxT + (size_t)NB*NS*600;
  if (ws_size < off) return;  // clean zero-output signal instead of OOB

  k_lengths<<<1, 256, 0, stream>>>(text, aspect, left, lens);
  k_cvt_emb<<<2048, 256, 0, stream>>>(emb, emb16);
  k_cvt_w<<<dim3(512, 3), 256, 0, stream>>>(Wih_f, Wih_b, Whh_f, Whh_b,
                                            bih_f, bhh_f, bih_b, bhh_b,
                                            Wih16, Whh_frag, bias_sum);
  k_inproj<<<dim3(272, 19), 256, 0, stream>>>(emb16, text, aspect, Wih16, bias_sum,
                                              lens, Pc, Pa);

  hipMemsetAsync(flags, 0, (size_t)(NS + NA)*8 * sizeof(int), stream);
  k_lstm_scan<<<dim3(19, 2, 8), 256, 0, stream>>>(Pc, Pa, Whh_frag, lens,
                                                  hcarC, hseqC, hcarA, hseqA, flags);

  k_combine_ctx<<<dim3(128, 16), 320, 0, stream>>>(hseqC, lens, ctx);
  k_transpose<<<dim3(256, 4, 19), 256, 0, stream>>>(ctx, ctxT);
  k_combine_asp<<<256, 320, 0, stream>>>(hseqA, lens, aspc);
  k_avg<<<256, 640, 0, stream>>>(ctx, aspc, lens, c_avg, a_avg);
  k_sw<<<dim3(32, 2), 640, 0, stream>>>(a_avg, c_avg, w1, w2, s1, s2);
  k_att_ctx<<<256, 128, 0, stream>>>(ctxT, ctx, s1, mca);
  k_att_asp<<<256, 512, 0, stream>>>(aspc, s2, mcc);
  k_u<<<256, 128, 0, stream>>>(ctxT, ctx, aspc, fc1_w, fc1_b, mfa, mfc);
  k_final<<<256, 192, 0, stream>>>(mca, mcc, mfa, mfc, fc2_w, fc2_b, out);
}

// Round 12
// 1616.502 us; speedup vs baseline: 1.4733x; 1.4733x over previous
//
#include <hip/hip_runtime.h>
#include <hip/hip_bf16.h>
#include <hip/hip_fp16.h>

// ---------------------------------------------------------------------------
// MGAN forward. fp16 MFMA; per-step-launch LSTM scan (js-partitioned, no LDS).
//   B=256 S=128 A=8 L=32 D=H=300 NC=3 VOCAB=32000
// MFMA 16x16x32_f16 fragment scheme (validated rounds 2-11):
//   A-frag: lane holds A[m = l&15][k = (l>>4)*8 + j]
//   B-frag (B^T [n][k]): lane holds B[n = l&15][k = (l>>4)*8 + j]
//   D:      lane,reg r -> D[m = (l>>4)*4 + r][n = l&15]
// P stored scan-order (validated r8-10): Pscan[d][t'][b][1216], b-major GEMM m.
// Whh fragment-major (validated r8-10). Scan: per-step launches (round-10
// structure, best measured: launch boundary = cheapest cross-XCD barrier;
// round-11 showed agent-scope fences cost more AND evict L2).
// Round 12: (a) emb f32->fp16 conversion fused into inproj A-frag gather
// (drops k_cvt_emb); (b) inproj epilogue remapped to 256B-contiguous write
// segments (was 32B scatter at 577 GB/s).
// ---------------------------------------------------------------------------

#define NB   256
#define NS   128
#define NA   8
#define NL   32
#define ND   300
#define NH   300
#define NPAD  2432      // 2*4*304 (bias/Wih padded n-space)
#define KP    320
#define TOK_CTX 32768
#define TOK_ALL 34816
#define PD    1216      // per-dir gate row: 4*304

typedef _Float16 half8 __attribute__((ext_vector_type(8)));
typedef float    f32x4 __attribute__((ext_vector_type(4)));

// ---------------- K0: sequence lengths ----------------
__global__ void k_lengths(const int* __restrict__ text, const int* __restrict__ aspect,
                          const int* __restrict__ left, int* __restrict__ lens) {
  int b = threadIdx.x;
  if (b >= NB) return;
  int ll = 0; for (int i = 0; i < NL; i++) ll += (left[b*NL + i] != 0);
  int cl = 0; for (int i = 0; i < NS; i++) cl += (text[b*NS + i] != 0);
  int al = 0; for (int i = 0; i < NA; i++) al += (aspect[b*NA + i] != 0);
  lens[b] = ll; lens[NB + b] = cl; lens[2*NB + b] = al;
}

// ---------------- converter: Wih / Whh_frag / bias ----------------
__global__ void k_cvt_w(const float* __restrict__ Wih_f, const float* __restrict__ Wih_b,
                        const float* __restrict__ Whh_f, const float* __restrict__ Whh_b,
                        const float* __restrict__ bih_f, const float* __restrict__ bhh_f,
                        const float* __restrict__ bih_b, const float* __restrict__ bhh_b,
                        _Float16* __restrict__ Wih16, _Float16* __restrict__ Whh_frag,
                        float* __restrict__ bias_sum) {
  int y = blockIdx.y;
  if (y == 0) {
    const long N = (long)NPAD * KP;
    for (long i = (long)blockIdx.x*blockDim.x + threadIdx.x; i < N; i += (long)gridDim.x*blockDim.x) {
      long row = i / KP; int k = (int)(i - row*KP);
      int d = (int)(row / PD); int rem = (int)(row - (long)d*PD);
      int g = rem / 304; int jj = rem - g*304;
      float v = 0.f;
      if (jj < NH && k < NH) {
        const float* src = d ? Wih_b : Wih_f;
        v = src[(long)(g*NH + jj)*NH + k];
      }
      Wih16[i] = (_Float16)v;
    }
  } else if (y == 1) {
    // Whh_frag[(((d*4+g)*19 + jt)*10 + k0)*512 + l*8 + e]
    //   n = jt*16 + (l&15), k = k0*32 + (l>>4)*8 + e
    const long N = (long)2*4*19*10*512;   // 778240
    for (long i = (long)blockIdx.x*blockDim.x + threadIdx.x; i < N; i += (long)gridDim.x*blockDim.x) {
      long q = i >> 9; int r512 = (int)(i & 511);
      int l = r512 >> 3, e = r512 & 7;
      int k0 = (int)(q % 10); q /= 10;
      int jt = (int)(q % 19); q /= 19;
      int g  = (int)(q % 4);  int d = (int)(q / 4);
      int n = jt*16 + (l & 15);
      int k = k0*32 + (l >> 4)*8 + e;
      float v = 0.f;
      if (n < NH && k < NH) {
        const float* src = d ? Whh_b : Whh_f;
        v = src[(long)(g*NH + n)*NH + k];
      }
      Whh_frag[i] = (_Float16)v;
    }
  } else {
    for (int i = blockIdx.x*blockDim.x + threadIdx.x; i < NPAD; i += gridDim.x*blockDim.x) {
      int d = i / PD; int rem = i - d*PD;
      int g = rem / 304; int jj = rem - g*304;
      float v = 0.f;
      if (jj < NH) {
        v = d ? (bih_b[g*NH + jj] + bhh_b[g*NH + jj]) : (bih_f[g*NH + jj] + bhh_f[g*NH + jj]);
      }
      bias_sum[i] = v;
    }
  }
}

// ---------------- K1: input projection GEMM (f32 emb gather fused) ----------------
// m enumerated b-major: ctx m = t*256 + b (m<32768); asp m-32768 = t*256 + b.
// grid (272 m, 19 n), 256 thr. Dest: Pc[d][t'][b][1216] / Pa[...]
__global__ __launch_bounds__(256) void k_inproj(
    const float* __restrict__ emb, const int* __restrict__ text, const int* __restrict__ aspect,
    const _Float16* __restrict__ Wih16, const float* __restrict__ bias_sum,
    const int* __restrict__ lens,
    _Float16* __restrict__ Pc, _Float16* __restrict__ Pa)
{
  const int l = threadIdx.x & 63, w = threadIdx.x >> 6;
  const int m0 = blockIdx.x * 128, n0 = blockIdx.y * 128;
  const int lrow = l & 15, lk = (l >> 4) * 8;
  __shared__ __align__(16) _Float16 Cs[128*136];

  const float* ap[2];
  #pragma unroll
  for (int q = 0; q < 2; q++) {
    int r = m0 + (2*w + q)*16 + lrow;
    int tok;
    if (r < TOK_CTX) { int t = r >> 8, b = r & 255; tok = text[b*NS + t]; }
    else { int rr = r - TOK_CTX; int t = rr >> 8, b = rr & 255; tok = aspect[b*NA + t]; }
    ap[q] = emb + (long)tok*ND;
  }
  const _Float16* bp[8];
  #pragma unroll
  for (int nt = 0; nt < 8; nt++)
    bp[nt] = Wih16 + (long)(n0 + nt*16 + lrow)*KP + lk;

  f32x4 acc[2][8];
  #pragma unroll
  for (int q = 0; q < 2; q++)
    #pragma unroll
    for (int nt = 0; nt < 8; nt++) acc[q][nt] = (f32x4){0.f,0.f,0.f,0.f};

  // k0 = 0..8: fully in-bounds (k <= 287+8 < 300 when lk<=24)
  #pragma unroll
  for (int k0 = 0; k0 < 9; k0++) {
    float4 f00 = *(const float4*)(ap[0] + k0*32 + lk);
    float4 f01 = *(const float4*)(ap[0] + k0*32 + lk + 4);
    float4 f10 = *(const float4*)(ap[1] + k0*32 + lk);
    float4 f11 = *(const float4*)(ap[1] + k0*32 + lk + 4);
    half8 a0, a1;
    a0[0]=(_Float16)f00.x; a0[1]=(_Float16)f00.y; a0[2]=(_Float16)f00.z; a0[3]=(_Float16)f00.w;
    a0[4]=(_Float16)f01.x; a0[5]=(_Float16)f01.y; a0[6]=(_Float16)f01.z; a0[7]=(_Float16)f01.w;
    a1[0]=(_Float16)f10.x; a1[1]=(_Float16)f10.y; a1[2]=(_Float16)f10.z; a1[3]=(_Float16)f10.w;
    a1[4]=(_Float16)f11.x; a1[5]=(_Float16)f11.y; a1[6]=(_Float16)f11.z; a1[7]=(_Float16)f11.w;
    #pragma unroll
    for (int nt = 0; nt < 8; nt++) {
      half8 bb = *(const half8*)(bp[nt] + k0*32);
      acc[0][nt] = __builtin_amdgcn_mfma_f32_16x16x32_f16(a0, bb, acc[0][nt], 0, 0, 0);
      acc[1][nt] = __builtin_amdgcn_mfma_f32_16x16x32_f16(a1, bb, acc[1][nt], 0, 0, 0);
    }
  }
  // k0 = 9: k = 288 + lk + j, guard k < 300 (emb rows are 300 f32)
  {
    half8 a0, a1;
    #pragma unroll
    for (int j = 0; j < 8; j++) {
      int k = 288 + lk + j;
      a0[j] = (k < ND) ? (_Float16)ap[0][k] : (_Float16)0.f;
      a1[j] = (k < ND) ? (_Float16)ap[1][k] : (_Float16)0.f;
    }
    #pragma unroll
    for (int nt = 0; nt < 8; nt++) {
      half8 bb = *(const half8*)(bp[nt] + 9*32);
      acc[0][nt] = __builtin_amdgcn_mfma_f32_16x16x32_f16(a0, bb, acc[0][nt], 0, 0, 0);
      acc[1][nt] = __builtin_amdgcn_mfma_f32_16x16x32_f16(a1, bb, acc[1][nt], 0, 0, 0);
    }
  }

  #pragma unroll
  for (int nt = 0; nt < 8; nt++) {
    float bias = bias_sum[n0 + nt*16 + lrow];
    #pragma unroll
    for (int q = 0; q < 2; q++) {
      int lr = (2*w + q)*16 + (l>>4)*4;
      #pragma unroll
      for (int r = 0; r < 4; r++)
        Cs[(lr + r)*136 + nt*16 + lrow] = (_Float16)(acc[q][nt][r] + bias);
    }
  }
  __syncthreads();

  // epilogue: lane = (r_sub = l>>4: 4 rows) x (chunk = l&15: 16 x 8 halves)
  // -> each store instr writes 4 x 256B-contiguous segments.
  const bool isCtx = (m0 < TOK_CTX);
  _Float16* __restrict__ Pdst = isCtx ? Pc : Pa;
  const int T2 = isCtx ? NS : NA;
  const int mrel = isCtx ? m0 : (m0 - TOK_CTX);
  const int tq = mrel >> 8;          // fixed per block (m0 is 128-aligned)
  const int b_base = mrel & 255;     // 0 or 128
  const int lenoff = isCtx ? NB : 2*NB;
  const int chunk = l & 15;
  const int col = n0 + chunk*8;      // 8-half chunk, within one dir (1216%8==0)
  const int d = (col >= PD) ? 1 : 0;
  const int rem = col - d*PD;
  #pragma unroll
  for (int it = 0; it < 8; it++) {
    const int row = w*32 + it*4 + (l >> 4);
    const int b = b_base + row;
    int tp = tq; bool doit = true;
    if (d == 1) {
      int len = lens[lenoff + b];
      if (tq < len) tp = len - 1 - tq; else doit = false;
    }
    if (doit) {
      half8 v = *(const half8*)&Cs[row*136 + chunk*8];
      *(half8*)&Pdst[((size_t)(d*T2 + tp)*256 + b)*PD + rem] = v;
    }
  }
}

// ---------------- K2: one LSTM time step (per-step launch, no LDS) ----------------
// grid (19 js, 2 d, z): z<4 -> ctx mg=z ; z>=4 -> asp mg=z-4 (only while t<8).
// block 256 = 4 waves; wave w owns batches [mg*64 + w*16, +16), gate-rows js*16..+15.
__global__ __launch_bounds__(256) void k_lstm_step(
    const _Float16* __restrict__ Pc, const _Float16* __restrict__ Pa,
    const _Float16* __restrict__ Whh_frag, const int* __restrict__ lens,
    _Float16* __restrict__ hcarC, float* __restrict__ cstC, _Float16* __restrict__ hseqC,
    _Float16* __restrict__ hcarA, float* __restrict__ cstA, _Float16* __restrict__ hseqA,
    int t)
{
  const int l = threadIdx.x & 63, w = threadIdx.x >> 6;
  const int js = blockIdx.x, d = blockIdx.y;
  const int which = blockIdx.z >> 2;
  const int mg = blockIdx.z & 3;
  const int T = which ? NA : NS;
  const _Float16* __restrict__ Pbase = which ? Pa : Pc;
  const int* __restrict__ lenp = lens + (which ? 2*NB : NB);
  _Float16* __restrict__ hcar = which ? hcarA : hcarC;
  float*    __restrict__ cst  = which ? cstA  : cstC;
  _Float16* __restrict__ hseq = which ? hseqA : hseqC;

  const int lrow = l & 15, lk = (l >> 4)*8, mrow = l >> 4;
  const int b0 = mg*64 + w*16;
  const int jj = js*16 + lrow;

  // ---- issue all independent loads first: P gates, c, h_prev, lens ----
  const size_t slab = (size_t)(d*T + t)*256;
  float pre[4][4];   // [r][g]
  float cp[4], hp[4];
  int   lenv[4];
  const _Float16* __restrict__ hr = hcar + ((size_t)(((t-1)&1)*2 + d)*256)*KP;
  #pragma unroll
  for (int r = 0; r < 4; r++) {
    const int b = b0 + mrow*4 + r;
    lenv[r] = lenp[b];
    const _Float16* Pr = Pbase + (slab + b)*PD + js*16 + lrow;
    pre[r][0] = (float)Pr[0];
    pre[r][1] = (float)Pr[304];
    pre[r][2] = (float)Pr[608];
    pre[r][3] = (float)Pr[912];
    if (t > 0) {
      cp[r] = cst[((size_t)d*256 + b)*304 + jj];
      hp[r] = (float)hr[(size_t)b*KP + jj];
    } else { cp[r] = 0.f; hp[r] = 0.f; }
  }

  // ---- MFMA: acc[g] = h_{t-1}[16 batches] @ Whh[g, js-slice]^T ----
  f32x4 acc[4];
  #pragma unroll
  for (int g = 0; g < 4; g++) acc[g] = (f32x4){0.f,0.f,0.f,0.f};
  if (t > 0) {
    const _Float16* hb = hr + (size_t)(b0 + lrow)*KP + lk;
    #pragma unroll
    for (int k0 = 0; k0 < 10; k0++) {
      half8 a = *(const half8*)(hb + k0*32);
      #pragma unroll
      for (int g = 0; g < 4; g++) {
        half8 bb = *(const half8*)(Whh_frag +
            ((((size_t)(d*4 + g)*19 + js)*10 + k0) << 9) + l*8);
        acc[g] = __builtin_amdgcn_mfma_f32_16x16x32_f16(a, bb, acc[g], 0, 0, 0);
      }
    }
  }

  // ---- pointwise: 4 cells per thread (r=0..3) ----
  _Float16* __restrict__ hw = hcar + ((size_t)((t&1)*2 + d)*256)*KP;
  #pragma unroll
  for (int r = 0; r < 4; r++) {
    const int b = b0 + mrow*4 + r;
    float gi = acc[0][r] + pre[r][0];
    float gf = acc[1][r] + pre[r][1];
    float gg = acc[2][r] + pre[r][2];
    float go = acc[3][r] + pre[r][3];
    float si = 1.f/(1.f + __expf(-gi));
    float sf = 1.f/(1.f + __expf(-gf));
    float so = 1.f/(1.f + __expf(-go));
    float cn = sf*cp[r] + si*tanhf(gg);
    float hn = so*tanhf(cn);
    bool mt = t < lenv[r];
    float h2 = mt ? hn : hp[r];
    float c2 = mt ? cn : cp[r];
    cst[((size_t)d*256 + b)*304 + jj] = c2;
    hw[(size_t)b*KP + jj] = (_Float16)h2;
    if (jj < NH)
      hseq[(((size_t)d*T + t)*256 + b)*NH + jj] = (_Float16)(mt ? hn : 0.f);
  }
}

// ---------------- K3: combine + position weight -> ctx[b][s][600] ----------------
__global__ __launch_bounds__(320) void k_combine_ctx(
    const _Float16* __restrict__ hseq, const int* __restrict__ lens, _Float16* __restrict__ ctx)
{
  const int s = blockIdx.x, bg = blockIdx.y, tid = threadIdx.x;
  if (tid >= NH) return;
  for (int bq = 0; bq < 16; bq++) {
    int b = bg*16 + bq;
    int cl = lens[NB + b], ll = lens[b], al = lens[2*NB + b];
    float clf = (float)cl, llf = (float)ll, alf = (float)al;
    float tf = (float)s, denom = clf - alf + 1.f;
    float wgt = (tf < llf) ? (1.f - (llf - tf)/denom)
              : (tf < llf + alf) ? 0.f
              : (tf < clf) ? (1.f - (tf - llf - alf + 1.f)/denom) : 0.f;
    float vf = (float)hseq[((size_t)s*256 + b)*NH + tid];
    int tb0 = cl - 1 - s; int tb = tb0 < 0 ? 0 : (tb0 > NS-1 ? NS-1 : tb0);
    float vb = (s < cl) ? (float)hseq[((size_t)(NS + tb)*256 + b)*NH + tid] : 0.f;
    ctx[((size_t)b*NS + s)*600 + tid]      = (_Float16)(vf * wgt);
    ctx[((size_t)b*NS + s)*600 + NH + tid] = (_Float16)(vb * wgt);
  }
}

// ---------------- K3b: transpose ctx -> ctxT[b][j][s] ----------------
__global__ void k_transpose(const _Float16* __restrict__ ctx, _Float16* __restrict__ ctxT) {
  __shared__ _Float16 tl[32][34];
  int b = blockIdx.x, s0 = blockIdx.y*32, j0 = blockIdx.z*32;
  int c = threadIdx.x & 31, r0 = threadIdx.x >> 5;
  #pragma unroll
  for (int i = 0; i < 4; i++) {
    int r = r0 + i*8;
    int j = j0 + c;
    tl[r][c] = (j < 600) ? ctx[((long)b*NS + s0 + r)*600 + j] : (_Float16)0.f;
  }
  __syncthreads();
  #pragma unroll
  for (int i = 0; i < 4; i++) {
    int r = r0 + i*8;
    int j = j0 + r;
    if (j < 600) ctxT[((long)b*600 + j)*NS + s0 + c] = tl[c][r];
  }
}

// ---------------- K4: aspect combine -> aspc[b][a][600] ----------------
__global__ __launch_bounds__(320) void k_combine_asp(
    const _Float16* __restrict__ hseq, const int* __restrict__ lens, _Float16* __restrict__ aspc)
{
  int b = blockIdx.x, tid = threadIdx.x;
  if (tid >= NH) return;
  int al = lens[2*NB + b];
  for (int a = 0; a < NA; a++) {
    float vf = (float)hseq[((size_t)a*256 + b)*NH + tid];
    int tb0 = al - 1 - a; int tb = tb0 < 0 ? 0 : (tb0 > NA-1 ? NA-1 : tb0);
    float vb = (a < al) ? (float)hseq[((size_t)(NA + tb)*256 + b)*NH + tid] : 0.f;
    aspc[((size_t)b*NA + a)*600 + tid]      = (_Float16)vf;
    aspc[((size_t)b*NA + a)*600 + NH + tid] = (_Float16)vb;
  }
}

// ---------------- K5: c_avg, a_avg ----------------
__global__ void k_avg(const _Float16* __restrict__ ctx, const _Float16* __restrict__ aspc,
                      const int* __restrict__ lens, float* __restrict__ c_avg, float* __restrict__ a_avg) {
  int b = blockIdx.x, j = threadIdx.x;
  if (j >= 600) return;
  float ac = 0.f;
  for (int s = 0; s < NS; s++) ac += (float)ctx[((long)b*NS + s)*600 + j];
  c_avg[(long)b*600 + j] = ac / (float)lens[NB + b];
  float aa = 0.f;
  for (int a = 0; a < NA; a++) aa += (float)aspc[((long)b*NA + a)*600 + j];
  a_avg[(long)b*600 + j] = aa / (float)lens[2*NB + b];
}

// ---------------- K6: s1 = a_avg@w1 ; s2 = c_avg@w2 ----------------
__global__ void k_sw(const float* __restrict__ a_avg, const float* __restrict__ c_avg,
                     const float* __restrict__ w1, const float* __restrict__ w2,
                     float* __restrict__ s1, float* __restrict__ s2) {
  __shared__ float src[8][600];
  int bg = blockIdx.x * 8, which = blockIdx.y, tid = threadIdx.x;
  const float* sp = which ? c_avg : a_avg;
  const float* w  = which ? w2 : w1;
  float* outp     = which ? s2 : s1;
  for (int u = tid; u < 8*600; u += 640) {
    int q = u / 600, dd = u - q*600;
    src[q][dd] = sp[(long)(bg + q)*600 + dd];
  }
  __syncthreads();
  int j = tid;
  if (j >= 600) return;
  float acc[8] = {0,0,0,0,0,0,0,0};
  for (int dd = 0; dd < 600; dd++) {
    float wvv = w[dd*600 + j];
    #pragma unroll
    for (int q = 0; q < 8; q++) acc[q] += src[q][dd] * wvv;
  }
  #pragma unroll
  for (int q = 0; q < 8; q++) outp[(long)(bg + q)*600 + j] = acc[q];
}

// ---------------- K7: alpha1 + mca ----------------
__global__ __launch_bounds__(128) void k_att_ctx(const _Float16* __restrict__ ctxT,
    const _Float16* __restrict__ ctx, const float* __restrict__ s1, float* __restrict__ mca) {
  int b = blockIdx.x, tid = threadIdx.x;
  __shared__ float sv[600];
  __shared__ float red[128];
  __shared__ float mx, sm;
  for (int u = tid; u < 600; u += 128) sv[u] = s1[(long)b*600 + u];
  __syncthreads();
  float sc = 0.f;
  for (int dd = 0; dd < 600; dd++) sc += sv[dd] * (float)ctxT[((long)b*600 + dd)*NS + tid];
  red[tid] = sc; __syncthreads();
  if (tid == 0) { float m = -1e30f; for (int i = 0; i < 128; i++) m = fmaxf(m, red[i]); mx = m; }
  __syncthreads();
  float e = __expf(sc - mx);
  red[tid] = e; __syncthreads();
  if (tid == 0) { float s = 0.f; for (int i = 0; i < 128; i++) s += red[i]; sm = s; }
  __syncthreads();
  float alpha = e / sm;
  red[tid] = alpha; __syncthreads();
  for (int i = 0; i < 5; i++) {
    int j = tid + i*128;
    if (j < 600) {
      float acc = 0.f;
      for (int s2 = 0; s2 < NS; s2++) acc += red[s2] * (float)ctx[((long)b*NS + s2)*600 + j];
      mca[(long)b*600 + j] = acc;
    }
  }
}

// ---------------- K8: alpha2 + mcc ----------------
__global__ void k_att_asp(const _Float16* __restrict__ aspc, const float* __restrict__ s2,
                          float* __restrict__ mcc) {
  int b = blockIdx.x, tid = threadIdx.x, wvv = tid >> 6, lane = tid & 63;
  __shared__ float sv[600];
  __shared__ float sc8[8];
  for (int u = tid; u < 600; u += 512) sv[u] = s2[(long)b*600 + u];
  __syncthreads();
  float p = 0.f;
  for (int dd = lane; dd < 600; dd += 64) p += sv[dd] * (float)aspc[((long)b*NA + wvv)*600 + dd];
  #pragma unroll
  for (int off = 32; off; off >>= 1) p += __shfl_down(p, off);
  if (lane == 0) sc8[wvv] = p;
  __syncthreads();
  float m = -1e30f;
  #pragma unroll
  for (int a = 0; a < 8; a++) m = fmaxf(m, sc8[a]);
  float es[8]; float ssum = 0.f;
  #pragma unroll
  for (int a = 0; a < 8; a++) { es[a] = __expf(sc8[a] - m); ssum += es[a]; }
  float inv = 1.f / ssum;
  for (int i = 0; i < 2; i++) {
    int j = tid + i*512;
    if (j < 600) {
      float acc = 0.f;
      #pragma unroll
      for (int a = 0; a < 8; a++) acc += es[a]*inv * (float)aspc[((long)b*NA + a)*600 + j];
      mcc[(long)b*600 + j] = acc;
    }
  }
}

// ---------------- K9: u tensor -> mfa, mfc ----------------
__global__ __launch_bounds__(128) void k_u(const _Float16* __restrict__ ctxT, const _Float16* __restrict__ ctx,
    const _Float16* __restrict__ aspc, const float* __restrict__ fc1_w, const float* __restrict__ fc1_b,
    float* __restrict__ mfa, float* __restrict__ mfc) {
  int b = blockIdx.x, tid = threadIdx.x;   // tid == s
  __shared__ __align__(16) float aspl[4800];
  __shared__ float ua8[8];
  __shared__ float red[128];
  __shared__ float qa8[8];
  __shared__ float mx1, sm1;
  __shared__ float pal[128][8];
  for (int u = tid; u < 4800; u += 128) {
    int a = u / 600, dd = u - a*600;
    aspl[dd*8 + a] = (float)aspc[((long)b*NA + a)*600 + dd];
  }
  __syncthreads();
  const float* wc = fc1_w;
  const float* wa = fc1_w + 600;
  const float* wm = fc1_w + 1200;
  {
    int wvv = tid >> 6, lane = tid & 63;
    for (int q = 0; q < 4; q++) {
      int a = wvv*4 + q;
      float p = 0.f;
      for (int dd = lane; dd < 600; dd += 64) p += wa[dd] * aspl[dd*8 + a];
      #pragma unroll
      for (int off = 32; off; off >>= 1) p += __shfl_down(p, off);
      if (lane == 0) ua8[a] = p;
    }
  }
  __syncthreads();
  float x8[8] = {0,0,0,0,0,0,0,0};
  float uc = 0.f;
  for (int dd = 0; dd < 600; dd++) {
    float cv = (float)ctxT[((long)b*600 + dd)*NS + tid];
    uc += cv * wc[dd];
    float cm = cv * wm[dd];
    float4 a03 = *(const float4*)&aspl[dd*8];
    float4 a47 = *(const float4*)&aspl[dd*8 + 4];
    x8[0] += cm*a03.x; x8[1] += cm*a03.y; x8[2] += cm*a03.z; x8[3] += cm*a03.w;
    x8[4] += cm*a47.x; x8[5] += cm*a47.y; x8[6] += cm*a47.z; x8[7] += cm*a47.w;
  }
  float fb = fc1_b[0];
  float u8v[8]; float umax = -1e30f;
  #pragma unroll
  for (int a = 0; a < 8; a++) { u8v[a] = uc + ua8[a] + x8[a] + fb; umax = fmaxf(umax, u8v[a]); }
  float pa[8]; float psum = 0.f;
  #pragma unroll
  for (int a = 0; a < 8; a++) { pa[a] = __expf(u8v[a] - umax); psum += pa[a]; }
  float pin = 1.f / psum;
  #pragma unroll
  for (int a = 0; a < 8; a++) pal[tid][a] = pa[a] * pin;
  red[tid] = umax;
  __syncthreads();
  if (tid == 0) { float m = -1e30f; for (int i = 0; i < 128; i++) m = fmaxf(m, red[i]); mx1 = m; }
  if (tid < 8) { float s = 0.f; for (int i = 0; i < 128; i++) s += pal[i][tid]; qa8[tid] = s * (1.f/128.f); }
  __syncthreads();
  float e = __expf(umax - mx1);
  red[tid] = e;
  __syncthreads();
  if (tid == 0) { float s = 0.f; for (int i = 0; i < 128; i++) s += red[i]; sm1 = s; }
  __syncthreads();
  float alpha = e / sm1;
  red[tid] = alpha;
  __syncthreads();
  for (int i = 0; i < 5; i++) {
    int j = tid + i*128;
    if (j < 600) {
      float am = 0.f;
      for (int s2 = 0; s2 < NS; s2++) am += red[s2] * (float)ctx[((long)b*NS + s2)*600 + j];
      float4 a03 = *(const float4*)&aspl[j*8];
      float4 a47 = *(const float4*)&aspl[j*8 + 4];
      mfa[(long)b*600 + j] = am;
      mfc[(long)b*600 + j] = qa8[0]*a03.x + qa8[1]*a03.y + qa8[2]*a03.z + qa8[3]*a03.w
                           + qa8[4]*a47.x + qa8[5]*a47.y + qa8[6]*a47.z + qa8[7]*a47.w;
    }
  }
}

// ---------------- K10: final FC + softmax ----------------
__global__ void k_final(const float* __restrict__ mca, const float* __restrict__ mcc,
                        const float* __restrict__ mfa, const float* __restrict__ mfc,
                        const float* __restrict__ fc2_w, const float* __restrict__ fc2_b,
                        float* __restrict__ out) {
  int b = blockIdx.x, tid = threadIdx.x, c = tid >> 6, lane = tid & 63;
  __shared__ float lg[3];
  float p = 0.f;
  for (int u = lane; u < 2400; u += 64) {
    int piece = u / 600;
    int jj = u - piece*600;
    const float* src = (piece == 0) ? mca : (piece == 1) ? mcc : (piece == 2) ? mfa : mfc;
    p += src[(long)b*600 + jj] * fc2_w[c*2400 + u];
  }
  #pragma unroll
  for (int off = 32; off; off >>= 1) p += __shfl_down(p, off);
  if (lane == 0) lg[c] = p + fc2_b[c];
  __syncthreads();
  if (tid == 0) {
    float m = fmaxf(lg[0], fmaxf(lg[1], lg[2]));
    float e0 = __expf(lg[0]-m), e1 = __expf(lg[1]-m), e2 = __expf(lg[2]-m);
    float s = e0 + e1 + e2;
    out[b*3 + 0] = e0/s; out[b*3 + 1] = e1/s; out[b*3 + 2] = e2/s;
  }
}

// ---------------- host ----------------
extern "C" void kernel_launch(void* const* d_in, const int* in_sizes, int n_in,
                              void* d_out, int out_size, void* d_ws, size_t ws_size,
                              hipStream_t stream)
{
  const int*   text    = (const int*)d_in[0];
  const int*   aspect  = (const int*)d_in[1];
  const int*   left    = (const int*)d_in[2];
  const float* emb     = (const float*)d_in[3];
  const float* Wih_f   = (const float*)d_in[4];
  const float* Whh_f   = (const float*)d_in[5];
  const float* bih_f   = (const float*)d_in[6];
  const float* bhh_f   = (const float*)d_in[7];
  const float* Wih_b   = (const float*)d_in[8];
  const float* Whh_b   = (const float*)d_in[9];
  const float* bih_b   = (const float*)d_in[10];
  const float* bhh_b   = (const float*)d_in[11];
  const float* w1      = (const float*)d_in[12];
  const float* w2      = (const float*)d_in[13];
  const float* fc1_w   = (const float*)d_in[14];
  const float* fc1_b   = (const float*)d_in[15];
  const float* fc2_w   = (const float*)d_in[16];
  const float* fc2_b   = (const float*)d_in[17];
  float* out = (float*)d_out;

  char* base = (char*)d_ws;
  size_t off = 0;
  auto alloc = [&](size_t bytes) -> void* {
    void* p = base + off;
    off = (off + bytes + 255) & ~(size_t)255;
    return p;
  };
  int*      lens     = (int*)     alloc(3 * NB * sizeof(int));
  float*    bias_sum = (float*)   alloc(NPAD * sizeof(float));
  _Float16* Wih16    = (_Float16*)alloc((size_t)NPAD*KP * sizeof(_Float16));      // 1.56 MB
  _Float16* Whh_frag = (_Float16*)alloc((size_t)2*4*19*10*512 * sizeof(_Float16));// 1.56 MB
  _Float16* hcarC    = (_Float16*)alloc((size_t)2*2*NB*KP * sizeof(_Float16));    // 655 KB
  _Float16* hcarA    = (_Float16*)alloc((size_t)2*2*NB*KP * sizeof(_Float16));
  float*    cstC     = (float*)   alloc((size_t)2*NB*304 * sizeof(float));        // 623 KB
  float*    cstA     = (float*)   alloc((size_t)2*NB*304 * sizeof(float));
  float*    c_avg    = (float*)   alloc((size_t)NB*600 * sizeof(float));
  float*    a_avg    = (float*)   alloc((size_t)NB*600 * sizeof(float));
  float*    s1       = (float*)   alloc((size_t)NB*600 * sizeof(float));
  float*    s2       = (float*)   alloc((size_t)NB*600 * sizeof(float));
  float*    mca      = (float*)   alloc((size_t)NB*600 * sizeof(float));
  float*    mcc      = (float*)   alloc((size_t)NB*600 * sizeof(float));
  float*    mfa      = (float*)   alloc((size_t)NB*600 * sizeof(float));
  float*    mfc      = (float*)   alloc((size_t)NB*600 * sizeof(float));
  _Float16* hseqC    = (_Float16*)alloc((size_t)2*NS*NB*NH * sizeof(_Float16));   // 39.3 MB
  _Float16* hseqA    = (_Float16*)alloc((size_t)2*NA*NB*NH * sizeof(_Float16));   // 2.46 MB
  // BIG region: Pc (159.4 MB) + Pa (10 MB); ctx/ctxT/aspc (81 MB) overlay Pc later
  _Float16* Pc = (_Float16*)alloc((size_t)2*NS*NB*PD * sizeof(_Float16));
  _Float16* Pa = (_Float16*)alloc((size_t)2*NA*NB*PD * sizeof(_Float16));
  _Float16* ctx  = Pc;
  _Float16* ctxT = ctx  + (size_t)NB*NS*600;
  _Float16* aspc = ctxT + (size_t)NB*NS*600;
  if (ws_size < off) return;  // clean zero-output signal instead of OOB

  k_lengths<<<1, 256, 0, stream>>>(text, aspect, left, lens);
  k_cvt_w<<<dim3(512, 3), 256, 0, stream>>>(Wih_f, Wih_b, Whh_f, Whh_b,
                                            bih_f, bhh_f, bih_b, bhh_b,
                                            Wih16, Whh_frag, bias_sum);
  k_inproj<<<dim3(272, 19), 256, 0, stream>>>(emb, text, aspect, Wih16, bias_sum,
                                              lens, Pc, Pa);

  for (int t = 0; t < NS; t++) {
    int z = (t < NA) ? 8 : 4;   // first 8 launches carry the aspect scan too
    k_lstm_step<<<dim3(19, 2, z), 256, 0, stream>>>(
        Pc, Pa, Whh_frag, lens, hcarC, cstC, hseqC, hcarA, cstA, hseqA, t);
  }

  k_combine_ctx<<<dim3(128, 16), 320, 0, stream>>>(hseqC, lens, ctx);
  k_transpose<<<dim3(256, 4, 19), 256, 0, stream>>>(ctx, ctxT);
  k_combine_asp<<<256, 320, 0, stream>>>(hseqA, lens, aspc);
  k_avg<<<256, 640, 0, stream>>>(ctx, aspc, lens, c_avg, a_avg);
  k_sw<<<dim3(32, 2), 640, 0, stream>>>(a_avg, c_avg, w1, w2, s1, s2);
  k_att_ctx<<<256, 128, 0, stream>>>(ctxT, ctx, s1, mca);
  k_att_asp<<<256, 512, 0, stream>>>(aspc, s2, mcc);
  k_u<<<256, 128, 0, stream>>>(ctxT, ctx, aspc, fc1_w, fc1_b, mfa, mfc);
  k_final<<<256, 192, 0, stream>>>(mca, mcc, mfa, mfc, fc2_w, fc2_b, out);
}